// Round 1
// baseline (477.542 us; speedup 1.0000x reference)
//
#include <hip/hip_runtime.h>

// Event voxelization (QuantizationLayerBinary):
//   events [N,4] float32 rows (x, y, t, p) -> vox[2*C*H*W] with set-to-1.0 scatter.
//   C=16, H=260, W=346. bin = ceil(t*C)-1, p in {-1,1} -> {0,1}.
//   Non-accumulating "set" => plain stores (all racers write 1.0f, benign).

#define CBINS 16
#define HDIM  260
#define WDIM  346
#define NVOX  (2 * CBINS * HDIM * WDIM)   // 2,878,720

__global__ __launch_bounds__(256) void zero_kernel(float4* __restrict__ out, int n4) {
    int i = blockIdx.x * blockDim.x + threadIdx.x;
    if (i < n4) out[i] = make_float4(0.f, 0.f, 0.f, 0.f);
}

__global__ __launch_bounds__(256) void scatter_kernel(const float4* __restrict__ ev,
                                                      float* __restrict__ out, int n) {
    int i = blockIdx.x * blockDim.x + threadIdx.x;
    if (i >= n) return;
    float4 e = ev[i];                      // x, y, t, p  (one coalesced 16B load)
    float t = e.z;
    if (t > 0.f && t <= 1.f) {
        int xi  = (int)e.x;
        int yi  = (int)e.y;
        int pi  = (e.w > 0.f) ? 1 : 0;     // (p_raw+1)*0.5 with p_raw in {-1,1}
        int bin = (int)ceilf(t * (float)CBINS) - 1;   // in [0,15] given valid t
        int idx = xi + WDIM * yi + WDIM * HDIM * (bin + CBINS * pi);
        out[idx] = 1.0f;
    }
}

extern "C" void kernel_launch(void* const* d_in, const int* in_sizes, int n_in,
                              void* d_out, int out_size, void* d_ws, size_t ws_size,
                              hipStream_t stream) {
    const float4* ev = (const float4*)d_in[0];
    float* out = (float*)d_out;
    int n_events = in_sizes[0] / 4;        // 16,000,000
    int n4 = out_size / 4;                 // 719,680 (NVOX divisible by 4)

    zero_kernel<<<(n4 + 255) / 256, 256, 0, stream>>>((float4*)d_out, n4);
    scatter_kernel<<<(n_events + 255) / 256, 256, 0, stream>>>(ev, out, n_events);
}

// Round 2
// 463.504 us; speedup vs baseline: 1.0303x; 1.0303x over previous
//
#include <hip/hip_runtime.h>

// Event voxelization (QuantizationLayerBinary):
//   events [N,4] float32 rows (x, y, t, p) -> vox[2*C*H*W] set-to-1.0 scatter.
//   C=16, H=260, W=346. bin = ceil(t*C)-1, p in {-1,1} -> {0,1}.
//
// R1 insight: direct 4B float scatter into 11.5 MB d_out caused 535 MB of HBM
// write traffic (doesn't fit per-XCD 4 MiB L2). Scatter into a 2.88 MB byte
// flag array in d_ws instead (L2-resident per XCD), then expand flags->floats.

#define CBINS 16
#define HDIM  260
#define WDIM  346
#define NVOX  (2 * CBINS * HDIM * WDIM)   // 2,878,720

__global__ __launch_bounds__(256) void scatter_flags(const float4* __restrict__ ev,
                                                     unsigned char* __restrict__ flags,
                                                     int n) {
    int i = blockIdx.x * blockDim.x + threadIdx.x;
    if (i >= n) return;
    float4 e = ev[i];                      // x, y, t, p  (one coalesced 16B load)
    float t = e.z;
    if (t > 0.f && t <= 1.f) {
        int xi  = (int)e.x;
        int yi  = (int)e.y;
        int pi  = (e.w > 0.f) ? 1 : 0;     // (p_raw+1)*0.5 with p_raw in {-1,1}
        int bin = (int)ceilf(t * (float)CBINS) - 1;   // in [0,15] given valid t
        int idx = xi + WDIM * yi + WDIM * HDIM * (bin + CBINS * pi);
        flags[idx] = 1;                    // benign race: all writers store 1
    }
}

// Expand 4 flag bytes -> 4 floats per thread (writes ALL of d_out, incl. zeros).
__global__ __launch_bounds__(256) void expand_flags(const uchar4* __restrict__ flags,
                                                    float4* __restrict__ out, int n4) {
    int i = blockIdx.x * blockDim.x + threadIdx.x;
    if (i >= n4) return;
    uchar4 f = flags[i];
    out[i] = make_float4(f.x ? 1.f : 0.f, f.y ? 1.f : 0.f,
                         f.z ? 1.f : 0.f, f.w ? 1.f : 0.f);
}

extern "C" void kernel_launch(void* const* d_in, const int* in_sizes, int n_in,
                              void* d_out, int out_size, void* d_ws, size_t ws_size,
                              hipStream_t stream) {
    const float4* ev = (const float4*)d_in[0];
    unsigned char* flags = (unsigned char*)d_ws;
    int n_events = in_sizes[0] / 4;        // 16,000,000
    int n4 = out_size / 4;                 // 719,680 (NVOX divisible by 4)

    hipMemsetAsync(flags, 0, NVOX, stream);                    // zero flag array
    scatter_flags<<<(n_events + 255) / 256, 256, 0, stream>>>(ev, flags, n_events);
    expand_flags<<<(n4 + 255) / 256, 256, 0, stream>>>((const uchar4*)flags,
                                                       (float4*)d_out, n4);
}

// Round 3
// 459.831 us; speedup vs baseline: 1.0385x; 1.0080x over previous
//
#include <hip/hip_runtime.h>

// Event voxelization (QuantizationLayerBinary):
//   events [N,4] float32 rows (x, y, t, p) -> vox[2*C*H*W] set-to-1.0 scatter.
//   C=16, H=260, W=346. bin = ceil(t*C)-1, p in {-1,1} -> {0,1}.
//
// R1: direct float scatter -> 548 MB HBM writes (output > per-XCD L2).
// R2: byte flags (2.88 MB) still thrashed: streaming 256 MB of event READS
//     through L2 evicted dirty flag lines (788 MB writeback). Fix: event
//     stream has zero reuse -> non-temporal loads (nt, no L2 allocate), so
//     flag lines stay resident. Output store in expand is streaming too ->
//     non-temporal stores.

#define CBINS 16
#define HDIM  260
#define WDIM  346
#define NVOX  (2 * CBINS * HDIM * WDIM)   // 2,878,720

typedef float fvec4 __attribute__((ext_vector_type(4)));

__global__ __launch_bounds__(256) void scatter_flags(const fvec4* __restrict__ ev,
                                                     unsigned char* __restrict__ flags,
                                                     int n) {
    int i = blockIdx.x * blockDim.x + threadIdx.x;
    if (i >= n) return;
    fvec4 e = __builtin_nontemporal_load(&ev[i]);   // x,y,t,p — nt: no L2 allocate
    float t = e.z;
    if (t > 0.f && t <= 1.f) {
        int xi  = (int)e.x;
        int yi  = (int)e.y;
        int pi  = (e.w > 0.f) ? 1 : 0;     // (p_raw+1)*0.5 with p_raw in {-1,1}
        int bin = (int)ceilf(t * (float)CBINS) - 1;   // in [0,15] given valid t
        int idx = xi + WDIM * yi + WDIM * HDIM * (bin + CBINS * pi);
        flags[idx] = 1;                    // benign race: all writers store 1
    }
}

// Expand 4 flag bytes -> 4 floats per thread (writes ALL of d_out, incl. zeros).
__global__ __launch_bounds__(256) void expand_flags(const uchar4* __restrict__ flags,
                                                    fvec4* __restrict__ out, int n4) {
    int i = blockIdx.x * blockDim.x + threadIdx.x;
    if (i >= n4) return;
    uchar4 f = flags[i];
    fvec4 v = { f.x ? 1.f : 0.f, f.y ? 1.f : 0.f,
                f.z ? 1.f : 0.f, f.w ? 1.f : 0.f };
    __builtin_nontemporal_store(v, &out[i]);        // streaming output, no reuse
}

extern "C" void kernel_launch(void* const* d_in, const int* in_sizes, int n_in,
                              void* d_out, int out_size, void* d_ws, size_t ws_size,
                              hipStream_t stream) {
    const fvec4* ev = (const fvec4*)d_in[0];
    unsigned char* flags = (unsigned char*)d_ws;
    int n_events = in_sizes[0] / 4;        // 16,000,000
    int n4 = out_size / 4;                 // 719,680 (NVOX divisible by 4)

    hipMemsetAsync(flags, 0, NVOX, stream);                    // zero flag array
    scatter_flags<<<(n_events + 255) / 256, 256, 0, stream>>>(ev, flags, n_events);
    expand_flags<<<(n4 + 255) / 256, 256, 0, stream>>>((const uchar4*)flags,
                                                       (fvec4*)d_out, n4);
}